// Round 5
// baseline (275.048 us; speedup 1.0000x reference)
//
#include <hip/hip_runtime.h>

#define PLANES 384
#define K 11
#define TS 88            // row stride in floats; rows in a wave differ by 4 -> skew (row&12) gives distinct bank-quads
#define ROWS 74          // 5 pad + 64 + 5 pad
#define TILEF (ROWS * TS + 16)   // floats per plane tile (26112 B)

// One 512-thread block = TWO (n,c) planes of 64x64. Warps 0-3 -> plane 2*bid,
// warps 4-7 -> plane 2*bid+1. Each half runs the proven round-0 kernel (4x4 output
// tiles, 48-VGPR codegen) on its own LDS tile/kernel/masks -> per-plane LDS traffic
// identical to round 0, but 8-wave blocks measure ~68% occupancy (R4 evidence)
// vs 43.5% for 4-wave blocks (R0). LDS 53.5 KB -> 3 blocks/CU = 24 waves/CU.
//
// R0-R4 evidence: duration is pinned at ~99us in both a low-occupancy/low-traffic
// regime (R0) and a high-occupancy/high-traffic regime (R4); HBM 19%, per-SIMD VALU
// ~17%, FMA work ~6% of budget. The only untested quadrant is high occupancy at
// R0's traffic level -- this kernel.
//
// LDS layout per tile: tile[row*TS + (row&12) + 8 + gx] = x[plane][row-5][gx]; halo
// zeroed. Window reads may spill <=4 floats past a row's stride into the next row's
// always-zero left-pad region; +16 array pad covers the last row.
__global__ __launch_bounds__(512, 6) void smpconv_kernel(
    const float* __restrict__ x,
    const float* __restrict__ wcoord,   // (1,4,2)
    const float* __restrict__ radius,   // (1,4,1,1)
    const float* __restrict__ wts,      // (1,384,4)
    float* __restrict__ out)
{
    __shared__ __align__(16) float tile[2][TILEF];     // 52224 B
    __shared__ __align__(16) float skv[2][12 * 12];    // 1152 B
    __shared__ int s_rcmask[2][K];                     // 88 B

    const int tid  = threadIdx.x;
    const int half = tid >> 8;           // 0/1: which plane this warp-group owns
    const int ltid = tid & 255;          // thread index within the half
    const int bid  = blockIdx.x;
    const int plane = bid * 2 + half;    // global plane index = n*384 + c
    const int c    = plane % PLANES;

    float* tl  = tile[half];
    float* sk  = skv[half];
    int*   rcm = s_rcmask[half];

    // ---- phase 0: zero LDS tile (halo = conv zero padding) ----
    #pragma unroll
    for (int z = 0; z < 7; ++z) {
        int e = z * 256 + ltid;
        if (e < TILEF / 4) {
            float4 zz; zz.x = zz.y = zz.z = zz.w = 0.f;
            *(float4*)&tl[e * 4] = zz;
        }
    }
    if (ltid < K) rcm[ltid] = 0;
    __syncthreads();

    // ---- phase 1: stage input plane (skewed) + generate this channel's 11x11 kernel ----
    const float* xp = x + (size_t)plane * 4096;
    #pragma unroll
    for (int it = 0; it < 4; ++it) {
        int e = it * 256 + ltid;             // float4 index 0..1023
        float4 v = ((const float4*)xp)[e];
        int gy = e >> 4;                     // 16 float4 per 64-wide row
        int gx = (e & 15) << 2;
        int row = gy + 5;
        *(float4*)&tl[row * TS + (row & 12) + 8 + gx] = v;
    }
    if (ltid < K * K) {
        // kf[c,i,j] = sum_p w[c,p] * relu(1 - (|wc0 - lin[j]| + |wc1 - lin[10-i]|)/r[p])
        int i = ltid / K;
        int j = ltid - i * K;
        float la = -1.f + 0.2f * (float)j;
        float lb = -1.f + 0.2f * (float)(10 - i);
        float a = 0.f;
        #pragma unroll
        for (int p = 0; p < 4; ++p) {
            float ir = 1.f / radius[p];
            float t = 1.f - (fabsf(wcoord[2*p] - la) + fabsf(wcoord[2*p+1] - lb)) * ir;
            t = fmaxf(t, 0.f);
            a = fmaf(wts[c*4 + p], t, a);
        }
        sk[i * 12 + j] = a;
        if (a != 0.f) atomicOr(&rcm[i], 1 << j);
    }
    __syncthreads();

    // ---- wave-uniform sparsity masks in SGPRs (scalar branches only; no conditional loads) ----
    int rc[K];
    int rowmask = 0;
    #pragma unroll
    for (int i = 0; i < K; ++i) {
        rc[i] = __builtin_amdgcn_readfirstlane(rcm[i]);
        if (rc[i]) rowmask |= 1 << i;
    }

    const int ty = ltid >> 4;    // 0..15 -> output rows 4ty..4ty+3
    const int tx = ltid & 15;    // 0..15 -> output cols 4tx..4tx+3

    float acc[4][4] = {};
    float kvs[4][12] = {};       // rotating cache of 4 kernel rows (fully unrolled -> regs)

    const float* colbase = tl + tx * 4;

    #pragma unroll
    for (int rr = 0; rr < 14; ++rr) {      // input rows 4ty+rr-5; kernel row i = rr-o
        // rotate in kernel row rr (UNCONDITIONAL quads when row active -> no cond-defined regs)
        if (rr < K) {
            if ((rowmask >> rr) & 1) {
                const int s = rr & 3;
                float4 k0 = *(const float4*)&sk[rr*12 + 0];
                float4 k1 = *(const float4*)&sk[rr*12 + 4];
                float4 k2 = *(const float4*)&sk[rr*12 + 8];
                kvs[s][0]=k0.x; kvs[s][1]=k0.y; kvs[s][2]=k0.z; kvs[s][3]=k0.w;
                kvs[s][4]=k1.x; kvs[s][5]=k1.y; kvs[s][6]=k1.z; kvs[s][7]=k1.w;
                kvs[s][8]=k2.x; kvs[s][9]=k2.y; kvs[s][10]=k2.z; kvs[s][11]=k2.w;
            }
        }
        // need bit (3-o) <=> kernel row i=rr-o exists and is nonzero
        const int need = ((rowmask << 3) >> rr) & 0xF;
        if (need) {
            const int row = ty * 4 + rr;
            const float* rp = colbase + row * TS + (row & 12);   // skewed row base
            float4 q0 = *(const float4*)(rp + 0);
            float4 q1 = *(const float4*)(rp + 4);
            float4 q2 = *(const float4*)(rp + 8);
            float4 q3 = *(const float4*)(rp + 12);
            float4 q4 = *(const float4*)(rp + 16);
            float w[20];
            w[0]=q0.x;  w[1]=q0.y;  w[2]=q0.z;  w[3]=q0.w;
            w[4]=q1.x;  w[5]=q1.y;  w[6]=q1.z;  w[7]=q1.w;
            w[8]=q2.x;  w[9]=q2.y;  w[10]=q2.z; w[11]=q2.w;
            w[12]=q3.x; w[13]=q3.y; w[14]=q3.z; w[15]=q3.w;
            w[16]=q4.x; w[17]=q4.y; w[18]=q4.z; w[19]=q4.w;
            #pragma unroll
            for (int o = 0; o < 4; ++o) {
                if (rr - o >= 0 && rr - o < K) {           // compile-time fold
                    if ((need >> (3 - o)) & 1) {
                        const int m = rc[rr - o];          // per-row column mask (SGPR)
                        const int s = (rr - o) & 3;
                        #pragma unroll
                        for (int j = 0; j < K; ++j) {
                            if ((m >> j) & 1) {            // scalar branch gates FMAs only
                                const float kv = kvs[s][j];
                                // plane col = 4tx+xx+j-5 -> window index xx+j+3
                                #pragma unroll
                                for (int xx = 0; xx < 4; ++xx)
                                    acc[o][xx] = fmaf(w[xx + j + 3], kv, acc[o][xx]);
                            }
                        }
                    }
                }
            }
        }
    }

    float* op = out + (size_t)plane * 4096 + (ty * 4) * 64 + tx * 4;
    #pragma unroll
    for (int o = 0; o < 4; ++o) {
        float4 v;
        v.x = acc[o][0]; v.y = acc[o][1]; v.z = acc[o][2]; v.w = acc[o][3];
        *(float4*)(op + o * 64) = v;
    }
}

extern "C" void kernel_launch(void* const* d_in, const int* in_sizes, int n_in,
                              void* d_out, int out_size, void* d_ws, size_t ws_size,
                              hipStream_t stream) {
    const float* x      = (const float*)d_in[0];
    const float* wcoord = (const float*)d_in[1];
    const float* radius = (const float*)d_in[2];
    const float* wts    = (const float*)d_in[3];
    float* out          = (float*)d_out;

    const int nblocks = 16 * PLANES / 2;   // 3072 blocks, two 64x64 planes each
    smpconv_kernel<<<dim3(nblocks), dim3(512), 0, stream>>>(x, wcoord, radius, wts, out);
}

// Round 6
// 222.026 us; speedup vs baseline: 1.2388x; 1.2388x over previous
//
#include <hip/hip_runtime.h>

#define PLANES 384
#define K 11
#define TS 88            // row stride in floats; rows in a wave differ by 4 -> skew (row&12) gives distinct bank-quads
#define ROWS 74          // 5 pad + 64 + 5 pad
#define TILEF (ROWS * TS + 16)   // floats per plane tile (26112 B)

// One 512-thread block = TWO (n,c) planes of 64x64. Warps 0-3 -> plane 2*bid,
// warps 4-7 -> plane 2*bid+1. Each half runs the round-0 structure (4x4 output
// tiles) on its own LDS tile/kernel/masks -> per-plane LDS traffic identical to
// round 0, with 8-wave blocks that measure ~68% occupancy (R4) vs 43.5% (R0).
// LDS 53.5 KB -> 3 blocks/CU = 24 waves/CU theoretical.
//
// R5 lesson (counter-proven): __launch_bounds__(512,6) made the allocator spill
// kvs[4][12] to scratch -> +286 MB HBM writes (1.57M threads x 192 B), dur 158us.
// Fix here is structural, not allocator-dependent: NO persistent kernel-row cache.
// Kernel-row quads are re-read from skv inside the o-loop as iteration-local
// temporaries (broadcast ds_read_b128, conflict-free per R2: conflicts identical
// 14.9M with or without b128 skv reads). Live set = acc[16]+w[20]+transients ~ 50.
//
// LDS layout per tile: tile[row*TS + (row&12) + 8 + gx] = x[plane][row-5][gx]; halo
// zeroed. Window reads may spill <=4 floats past a row's stride into the next row's
// always-zero left-pad region; +16 array pad covers the last row.
__global__ __launch_bounds__(512) void smpconv_kernel(
    const float* __restrict__ x,
    const float* __restrict__ wcoord,   // (1,4,2)
    const float* __restrict__ radius,   // (1,4,1,1)
    const float* __restrict__ wts,      // (1,384,4)
    float* __restrict__ out)
{
    __shared__ __align__(16) float tile[2][TILEF];     // 52224 B
    __shared__ __align__(16) float skv[2][12 * 12];    // 1152 B
    __shared__ int s_rcmask[2][K];                     // 88 B

    const int tid  = threadIdx.x;
    const int half = tid >> 8;           // 0/1: which plane this warp-group owns
    const int ltid = tid & 255;          // thread index within the half
    const int bid  = blockIdx.x;
    const int plane = bid * 2 + half;    // global plane index = n*384 + c
    const int c    = plane % PLANES;

    float* tl  = tile[half];
    float* sk  = skv[half];
    int*   rcm = s_rcmask[half];

    // ---- phase 0: zero LDS tile (halo = conv zero padding) ----
    #pragma unroll
    for (int z = 0; z < 7; ++z) {
        int e = z * 256 + ltid;
        if (e < TILEF / 4) {
            float4 zz; zz.x = zz.y = zz.z = zz.w = 0.f;
            *(float4*)&tl[e * 4] = zz;
        }
    }
    if (ltid < K) rcm[ltid] = 0;
    __syncthreads();

    // ---- phase 1: stage input plane (skewed) + generate this channel's 11x11 kernel ----
    const float* xp = x + (size_t)plane * 4096;
    #pragma unroll
    for (int it = 0; it < 4; ++it) {
        int e = it * 256 + ltid;             // float4 index 0..1023
        float4 v = ((const float4*)xp)[e];
        int gy = e >> 4;                     // 16 float4 per 64-wide row
        int gx = (e & 15) << 2;
        int row = gy + 5;
        *(float4*)&tl[row * TS + (row & 12) + 8 + gx] = v;
    }
    if (ltid < K * K) {
        // kf[c,i,j] = sum_p w[c,p] * relu(1 - (|wc0 - lin[j]| + |wc1 - lin[10-i]|)/r[p])
        int i = ltid / K;
        int j = ltid - i * K;
        float la = -1.f + 0.2f * (float)j;
        float lb = -1.f + 0.2f * (float)(10 - i);
        float a = 0.f;
        #pragma unroll
        for (int p = 0; p < 4; ++p) {
            float ir = 1.f / radius[p];
            float t = 1.f - (fabsf(wcoord[2*p] - la) + fabsf(wcoord[2*p+1] - lb)) * ir;
            t = fmaxf(t, 0.f);
            a = fmaf(wts[c*4 + p], t, a);
        }
        sk[i * 12 + j] = a;
        if (a != 0.f) atomicOr(&rcm[i], 1 << j);
    }
    __syncthreads();

    // ---- wave-uniform sparsity masks in SGPRs (scalar branches only; no conditional loads) ----
    int rc[K];
    int rowmask = 0;
    #pragma unroll
    for (int i = 0; i < K; ++i) {
        rc[i] = __builtin_amdgcn_readfirstlane(rcm[i]);
        if (rc[i]) rowmask |= 1 << i;
    }

    const int ty = ltid >> 4;    // 0..15 -> output rows 4ty..4ty+3
    const int tx = ltid & 15;    // 0..15 -> output cols 4tx..4tx+3

    float acc[4][4] = {};

    const float* colbase = tl + tx * 4;

    #pragma unroll
    for (int rr = 0; rr < 14; ++rr) {      // input rows 4ty+rr-5; kernel row i = rr-o
        // need bit (3-o) <=> kernel row i=rr-o exists and is nonzero
        const int need = ((rowmask << 3) >> rr) & 0xF;
        if (need) {
            const int row = ty * 4 + rr;
            const float* rp = colbase + row * TS + (row & 12);   // skewed row base
            float4 q0 = *(const float4*)(rp + 0);
            float4 q1 = *(const float4*)(rp + 4);
            float4 q2 = *(const float4*)(rp + 8);
            float4 q3 = *(const float4*)(rp + 12);
            float4 q4 = *(const float4*)(rp + 16);
            float w[20];
            w[0]=q0.x;  w[1]=q0.y;  w[2]=q0.z;  w[3]=q0.w;
            w[4]=q1.x;  w[5]=q1.y;  w[6]=q1.z;  w[7]=q1.w;
            w[8]=q2.x;  w[9]=q2.y;  w[10]=q2.z; w[11]=q2.w;
            w[12]=q3.x; w[13]=q3.y; w[14]=q3.z; w[15]=q3.w;
            w[16]=q4.x; w[17]=q4.y; w[18]=q4.z; w[19]=q4.w;
            #pragma unroll
            for (int o = 0; o < 4; ++o) {
                const int i = rr - o;
                if (i >= 0 && i < K) {                     // compile-time fold
                    if ((need >> (3 - o)) & 1) {
                        const int m = rc[i];               // per-row column mask (SGPR)
                        // per-use broadcast read of kernel row i (iteration-local ->
                        // cannot be spilled; conflict-free broadcast)
                        const float4 k0 = *(const float4*)&sk[i*12 + 0];
                        const float4 k1 = *(const float4*)&sk[i*12 + 4];
                        const float4 k2 = *(const float4*)&sk[i*12 + 8];
                        const float kk[12] = {k0.x,k0.y,k0.z,k0.w,
                                              k1.x,k1.y,k1.z,k1.w,
                                              k2.x,k2.y,k2.z,k2.w};
                        #pragma unroll
                        for (int j = 0; j < K; ++j) {
                            if ((m >> j) & 1) {            // scalar branch gates FMAs only
                                const float kv = kk[j];    // static index after unroll
                                // plane col = 4tx+xx+j-5 -> window index xx+j+3
                                #pragma unroll
                                for (int xx = 0; xx < 4; ++xx)
                                    acc[o][xx] = fmaf(w[xx + j + 3], kv, acc[o][xx]);
                            }
                        }
                    }
                }
            }
        }
    }

    float* op = out + (size_t)plane * 4096 + (ty * 4) * 64 + tx * 4;
    #pragma unroll
    for (int o = 0; o < 4; ++o) {
        float4 v;
        v.x = acc[o][0]; v.y = acc[o][1]; v.z = acc[o][2]; v.w = acc[o][3];
        *(float4*)(op + o * 64) = v;
    }
}

extern "C" void kernel_launch(void* const* d_in, const int* in_sizes, int n_in,
                              void* d_out, int out_size, void* d_ws, size_t ws_size,
                              hipStream_t stream) {
    const float* x      = (const float*)d_in[0];
    const float* wcoord = (const float*)d_in[1];
    const float* radius = (const float*)d_in[2];
    const float* wts    = (const float*)d_in[3];
    float* out          = (float*)d_out;

    const int nblocks = 16 * PLANES / 2;   // 3072 blocks, two 64x64 planes each
    smpconv_kernel<<<dim3(nblocks), dim3(512), 0, stream>>>(x, wcoord, radius, wts, out);
}

// Round 7
// 211.141 us; speedup vs baseline: 1.3027x; 1.0516x over previous
//
#include <hip/hip_runtime.h>

#define PLANES 384
#define K 11
#define TS 88            // row stride in floats; 88 ≡ 24 banks, ×4 rows ≡ 0 mod 32 -> skew must separate
#define ROWS 74          // 5 pad + 64 + 5 pad

// One block = one (n,c) plane of 64x64. 256 threads, each computes a 4x4 output tile.
// LDS layout: tile[row*TS + sk2(row) + 8 + col] = x[plane][row-5][col], sk2 = (row&12)>>1.
// Halo zeroed (conv zero padding).
//
// BANK FIX (R7): the old b128 window reads with additive skew (row&12) were an 8-way
// conflict: skew ≡ 0 mod 4 banks (b128 needs 16B align), stride-16B lanes use only
// banks ≡ 0 mod 4, and all 4 row-groups of a wave share that same 8-bank set
// (88*4 ≡ 0 mod 32). Measured +15 cy per b128 (14.9M conflicts / 983K instrs),
// matching m136's 8-way = 2.94x. Half-grain skew {0,2,4,6} is legal for b64 (8B align)
// and puts the 4 row-groups on disjoint bank sets -> exactly 4 accesses/bank per
// 512B op = the 4-cycle floor. Window = 8 x float2 (16 floats), staging = 2 x float2.
__global__ __launch_bounds__(256) void smpconv_kernel(
    const float* __restrict__ x,
    const float* __restrict__ wcoord,   // (1,4,2)
    const float* __restrict__ radius,   // (1,4,1,1)
    const float* __restrict__ wts,      // (1,384,4)
    float* __restrict__ out)
{
    __shared__ __align__(16) float tile[ROWS * TS + 16];   // 26176 B
    __shared__ __align__(16) float skv[12 * 12];           // 11 kernel rows, stride 12
    __shared__ int s_rcmask[K];                            // per-kernel-row column bitmask

    const int tid = threadIdx.x;
    const int bid = blockIdx.x;          // n*384 + c
    const int c   = bid % PLANES;

    // ---- phase 0: zero LDS tile (halo = conv zero padding) ----
    #pragma unroll
    for (int z = 0; z < 7; ++z) {
        int e = z * 256 + tid;
        if (e < (ROWS * TS + 16) / 4) {
            float4 zz; zz.x = zz.y = zz.z = zz.w = 0.f;
            *(float4*)&tile[e * 4] = zz;
        }
    }
    if (tid < K) s_rcmask[tid] = 0;
    __syncthreads();

    // ---- phase 1: stage input plane (half-grain skew; b64 stores, contiguous per
    //      row-group -> conflict-free) + generate this channel's 11x11 kernel ----
    const float* xp = x + (size_t)bid * 4096;
    #pragma unroll
    for (int it = 0; it < 4; ++it) {
        int e = it * 256 + tid;              // float4 index 0..1023
        float4 v = ((const float4*)xp)[e];
        int gy = e >> 4;                     // 16 float4 per 64-wide row
        int gx = (e & 15) << 2;
        int row = gy + 5;
        int idx = row * TS + ((row & 12) >> 1) + 8 + gx;   // even but not 16B-aligned
        float2 lo; lo.x = v.x; lo.y = v.y;
        float2 hi; hi.x = v.z; hi.y = v.w;
        *(float2*)&tile[idx + 0] = lo;
        *(float2*)&tile[idx + 2] = hi;
    }
    if (tid < K * K) {
        // kf[c,i,j] = sum_p w[c,p] * relu(1 - (|wc0 - lin[j]| + |wc1 - lin[10-i]|)/r[p])
        int i = tid / K;
        int j = tid - i * K;
        float la = -1.f + 0.2f * (float)j;
        float lb = -1.f + 0.2f * (float)(10 - i);
        float a = 0.f;
        #pragma unroll
        for (int p = 0; p < 4; ++p) {
            float ir = 1.f / radius[p];
            float t = 1.f - (fabsf(wcoord[2*p] - la) + fabsf(wcoord[2*p+1] - lb)) * ir;
            t = fmaxf(t, 0.f);
            a = fmaf(wts[c*4 + p], t, a);
        }
        skv[i * 12 + j] = a;
        if (a != 0.f) atomicOr(&s_rcmask[i], 1 << j);
    }
    __syncthreads();

    // ---- wave-uniform sparsity masks in SGPRs (scalar branches only; no conditional loads) ----
    int rc[K];
    int rowmask = 0;
    #pragma unroll
    for (int i = 0; i < K; ++i) {
        rc[i] = __builtin_amdgcn_readfirstlane(s_rcmask[i]);
        if (rc[i]) rowmask |= 1 << i;
    }

    const int ty = tid >> 4;     // 0..15 -> output rows 4ty..4ty+3
    const int tx = tid & 15;     // 0..15 -> output cols 4tx..4tx+3

    float acc[4][4] = {};
    float kvs[4][12] = {};       // rotating cache of 4 kernel rows (fully unrolled -> regs)

    // window base: stored col (4tx-6) = row*TS + sk2 + 8 + (4tx-6) = row*TS + sk2 + (4tx+2)
    const float* colbase = tile + tx * 4 + 2;

    #pragma unroll
    for (int rr = 0; rr < 14; ++rr) {      // input rows 4ty+rr-5; kernel row i = rr-o
        // rotate in kernel row rr (UNCONDITIONAL quads when row active -> no cond-defined regs)
        if (rr < K) {
            if ((rowmask >> rr) & 1) {
                const int s = rr & 3;
                float4 k0 = *(const float4*)&skv[rr*12 + 0];
                float4 k1 = *(const float4*)&skv[rr*12 + 4];
                float4 k2 = *(const float4*)&skv[rr*12 + 8];
                kvs[s][0]=k0.x; kvs[s][1]=k0.y; kvs[s][2]=k0.z; kvs[s][3]=k0.w;
                kvs[s][4]=k1.x; kvs[s][5]=k1.y; kvs[s][6]=k1.z; kvs[s][7]=k1.w;
                kvs[s][8]=k2.x; kvs[s][9]=k2.y; kvs[s][10]=k2.z; kvs[s][11]=k2.w;
            }
        }
        // need bit (3-o) <=> kernel row i=rr-o exists and is nonzero
        const int need = ((rowmask << 3) >> rr) & 0xF;
        if (need) {
            const int row = ty * 4 + rr;
            // rp points at stored col 4tx-6; all offsets even -> b64 reads, half-grain
            // skew makes the 4 row-groups of the wave hit disjoint bank sets.
            const float* rp = colbase + row * TS + ((row & 12) >> 1);
            float2 p0 = *(const float2*)(rp + 0);
            float2 p1 = *(const float2*)(rp + 2);
            float2 p2 = *(const float2*)(rp + 4);
            float2 p3 = *(const float2*)(rp + 6);
            float2 p4 = *(const float2*)(rp + 8);
            float2 p5 = *(const float2*)(rp + 10);
            float2 p6 = *(const float2*)(rp + 12);
            float2 p7 = *(const float2*)(rp + 14);
            float w[16];
            w[0]=p0.x;  w[1]=p0.y;  w[2]=p1.x;  w[3]=p1.y;
            w[4]=p2.x;  w[5]=p2.y;  w[6]=p3.x;  w[7]=p3.y;
            w[8]=p4.x;  w[9]=p4.y;  w[10]=p5.x; w[11]=p5.y;
            w[12]=p6.x; w[13]=p6.y; w[14]=p7.x; w[15]=p7.y;
            #pragma unroll
            for (int o = 0; o < 4; ++o) {
                if (rr - o >= 0 && rr - o < K) {           // compile-time fold
                    if ((need >> (3 - o)) & 1) {
                        const int m = rc[rr - o];          // per-row column mask (SGPR)
                        const int s = (rr - o) & 3;
                        #pragma unroll
                        for (int j = 0; j < K; ++j) {
                            if ((m >> j) & 1) {            // scalar branch gates FMAs only
                                const float kv = kvs[s][j];
                                // plane col = 4tx+xx+j-5; stored col rel rp = xx+j+1
                                #pragma unroll
                                for (int xx = 0; xx < 4; ++xx)
                                    acc[o][xx] = fmaf(w[1 + xx + j], kv, acc[o][xx]);
                            }
                        }
                    }
                }
            }
        }
    }

    float* op = out + (size_t)bid * 4096 + (ty * 4) * 64 + tx * 4;
    #pragma unroll
    for (int o = 0; o < 4; ++o) {
        float4 v;
        v.x = acc[o][0]; v.y = acc[o][1]; v.z = acc[o][2]; v.w = acc[o][3];
        *(float4*)(op + o * 64) = v;
    }
}

extern "C" void kernel_launch(void* const* d_in, const int* in_sizes, int n_in,
                              void* d_out, int out_size, void* d_ws, size_t ws_size,
                              hipStream_t stream) {
    const float* x      = (const float*)d_in[0];
    const float* wcoord = (const float*)d_in[1];
    const float* radius = (const float*)d_in[2];
    const float* wts    = (const float*)d_in[3];
    float* out          = (float*)d_out;

    const int nplanes = 16 * PLANES;   // 6144 blocks, one 64x64 plane each
    smpconv_kernel<<<dim3(nplanes), dim3(256), 0, stream>>>(x, wcoord, radius, wts, out);
}